// Round 9
// baseline (198.994 us; speedup 1.0000x reference)
//
#include <hip/hip_runtime.h>
#include <math.h>

// ============================================================================
// MultiHeadDistanceLayer — v7
//  attn: in-block K-split. 512 thr = 8 waves; waves 0-3 even K-tiles, 4-7 odd,
//    each group has its own double-buffered LDS K-tile (XOR swizzle). 32 q per
//    wave, q-tile 128, grid 512 (16 waves/CU = 4/SIMD). Inline gaussian prior,
//    no-max exp-sum softmax (scores bounded => exact via shift-invariance).
//    Cross-group merge via 2KB LDS + one barrier.
//  proj: v4-proven projB (fp32 x/W, per-ks LDS W transpose, 3-pass bf16 MFMA).
// ============================================================================

#define B_  4
#define L_  2048
#define D_  256
#define H_  8
#define HD_ 64

typedef unsigned int u32;
typedef unsigned short u16;
typedef short bf16x8 __attribute__((ext_vector_type(8)));
typedef float f32x4  __attribute__((ext_vector_type(4)));

__device__ __forceinline__ u16 bf16rne(float v) {
    u32 u = __float_as_uint(v);
    return (u16)((u + 0x7fffu + ((u >> 16) & 1u)) >> 16);
}
__device__ __forceinline__ float bf2f(u16 h) { return __uint_as_float(((u32)h) << 16); }

#if __has_builtin(__builtin_amdgcn_exp2f)
__device__ __forceinline__ float fast_exp2(float x) { return __builtin_amdgcn_exp2f(x); }
#else
__device__ __forceinline__ float fast_exp2(float x) { return exp2f(x); }
#endif

// ---------------------------------------------------------------------------
// projB (proven v4): Q/K = x@W + b, 3-pass bf16 MFMA, per-ks LDS W transpose.
// grid (64 m-tiles of 128, 8 heads, 2 {Q,K}), 256 thr.
// ---------------------------------------------------------------------------
__global__ __launch_bounds__(256, 4) void projB_kernel(
    const float* __restrict__ x,
    const float* __restrict__ Wq, const float* __restrict__ bq,
    const float* __restrict__ Wk, const float* __restrict__ bk,
    u16* __restrict__ Qhi, u16* __restrict__ Qlo,
    u16* __restrict__ Khi, u16* __restrict__ Klo)
{
    __shared__ __align__(16) u16 Bs[2][64][40];

    const int z = blockIdx.z;
    const float* W    = z ? Wk : Wq;
    const float* bias = z ? bk : bq;
    u16* Ohi = z ? Khi : Qhi;
    u16* Olo = z ? Klo : Qlo;

    const int t = threadIdx.x, w = t >> 6, l = t & 63;
    const int kc = l & 15, lhi = l >> 4;
    const int m0 = blockIdx.x * 128 + w * 32;
    const int h  = blockIdx.y;

    const float* xp0 = x + (size_t)(m0 + kc) * D_;
    const float* xp1 = x + (size_t)(m0 + 16 + kc) * D_;

    f32x4 acc[2][4];
    #pragma unroll
    for (int mf = 0; mf < 2; ++mf)
        #pragma unroll
        for (int nf = 0; nf < 4; ++nf) acc[mf][nf] = (f32x4){0.f, 0.f, 0.f, 0.f};

    for (int ks = 0; ks < 8; ++ks) {
        __syncthreads();
        #pragma unroll
        for (int j = 0; j < 2; ++j) {
            const int fid = t + j * 256;
            const int kr = fid >> 4, c4 = fid & 15;
            float4 v = *(const float4*)&W[(size_t)(ks*32 + kr) * 512 + h*64 + c4*4];
            float vv[4] = {v.x, v.y, v.z, v.w};
            #pragma unroll
            for (int e = 0; e < 4; ++e) {
                const int n = c4*4 + e;
                const u16 hi = bf16rne(vv[e]);
                Bs[0][n][kr] = hi;
                Bs[1][n][kr] = bf16rne(vv[e] - bf2f(hi));
            }
        }
        __syncthreads();

        union { u16 u[8]; bf16x8 v; } ah[2], al[2];
        #pragma unroll
        for (int mf = 0; mf < 2; ++mf) {
            const float* xp = mf ? xp1 : xp0;
            float4 a = *(const float4*)(xp + ks*32 + lhi*8);
            float4 b = *(const float4*)(xp + ks*32 + lhi*8 + 4);
            float vv[8] = {a.x, a.y, a.z, a.w, b.x, b.y, b.z, b.w};
            #pragma unroll
            for (int e = 0; e < 8; ++e) {
                const u16 hi = bf16rne(vv[e]);
                ah[mf].u[e] = hi;
                al[mf].u[e] = bf16rne(vv[e] - bf2f(hi));
            }
        }

        #pragma unroll
        for (int nf = 0; nf < 4; ++nf) {
            const bf16x8 bh = *(const bf16x8*)&Bs[0][nf*16 + kc][lhi*8];
            const bf16x8 bl = *(const bf16x8*)&Bs[1][nf*16 + kc][lhi*8];
            #pragma unroll
            for (int mf = 0; mf < 2; ++mf) {
                acc[mf][nf] = __builtin_amdgcn_mfma_f32_16x16x32_bf16(ah[mf].v, bh, acc[mf][nf], 0, 0, 0);
                acc[mf][nf] = __builtin_amdgcn_mfma_f32_16x16x32_bf16(ah[mf].v, bl, acc[mf][nf], 0, 0, 0);
                acc[mf][nf] = __builtin_amdgcn_mfma_f32_16x16x32_bf16(al[mf].v, bh, acc[mf][nf], 0, 0, 0);
            }
        }
    }

    #pragma unroll
    for (int mf = 0; mf < 2; ++mf)
        #pragma unroll
        for (int nf = 0; nf < 4; ++nf) {
            const float bv = bias[h * 64 + nf*16 + kc];
            #pragma unroll
            for (int r = 0; r < 4; ++r) {
                const float v = acc[mf][nf][r] + bv;
                const u16 hi = bf16rne(v);
                const u16 lo = bf16rne(v - bf2f(hi));
                const int m = m0 + mf*16 + lhi*4 + r;
                const int bb = m >> 11, ll = m & (L_ - 1);
                const size_t o = (((size_t)h * B_ + bb) * L_ + ll) * HD_ + nf*16 + kc;
                Ohi[o] = hi; Olo[o] = lo;
            }
        }
}

// ---------------------------------------------------------------------------
// attn v7: grid 512 (16 q-tiles of 128 x 32 hb, XCD-grouped), 512 thr.
// Waves 0-3: q rows (w&3)*32, even K-tiles; waves 4-7: same q, odd K-tiles.
// Per-group double-buffered LDS. Inline prior. Cross-group LDS merge.
// ---------------------------------------------------------------------------
__global__ __launch_bounds__(512, 4) void attn_kernel(
    const u16* __restrict__ Qhi, const u16* __restrict__ Qlo,
    const u16* __restrict__ Khi, const u16* __restrict__ Klo,
    const float* __restrict__ prior_mean, const float* __restrict__ log_prior_std,
    const int* __restrict__ max_len, float* __restrict__ out)
{
    __shared__ __align__(16) u16 kls[2][2][2][4096];   // [kg][buf][plane], 64 KB
    __shared__ float2 red2[2][128];                    // cross-group merge, 2 KB

    const int t = threadIdx.x, w = t >> 6, l = t & 63;
    const int kc = l & 15, lhi = l >> 4;
    const int kg = w >> 2;                    // k-group: 0 = even tiles, 1 = odd
    const int w4 = w & 3;

    const int p = blockIdx.x;                 // XCD-grouped decode: 64 blk/XCD
    const int xcd = p & 7, s = p >> 3;        // s in [0,64)
    const int hb = xcd * 4 + (s >> 4);        // 4 hb per XCD
    const int q0 = (s & 15) * 128;            // 16 q-tiles of 128
    const int h = hb >> 2, b = hb & 3;
    const int qw = q0 + w4 * 32;

    const float iml = 1.0f / (float)(*max_len);
    const float mu  = prior_mean[h];
    const float sg  = __expf(log_prior_std[h]);
    const float isg = 1.0f / sg;
    // pr = exp2(LC - t2^2), t2 = delta*A2 + B2  => P*0.125*log2e
    const float S2  = 0.84932180f;                       // sqrt(0.5*log2e)
    const float A2  = iml * isg * S2;
    const float B2  = -mu * isg * S2;
    const float LC  = __log2f(0.125f * 1.44269504089f / (sg * 2.5066282746310002f));

    // ---- Q fragments: [qf][dh] hi and lo ----
    bf16x8 qh[2][2], ql2[2][2];
    #pragma unroll
    for (int qf = 0; qf < 2; ++qf)
        #pragma unroll
        for (int dh = 0; dh < 2; ++dh) {
            const size_t qo = ((size_t)hb * L_ + qw + qf*16 + kc) * HD_ + dh*32 + lhi*8;
            qh[qf][dh]  = *(const bf16x8*)&Qhi[qo];
            ql2[qf][dh] = *(const bf16x8*)&Qlo[qo];
        }

    // delta = TI*64 + cc + d0q[qf], cc = kf*16 + r  (k row includes lhi*4)
    const int d0q0 = lhi*4 - (qw + kc);
    const int d0q1 = d0q0 - 16;

    // ---- staging: per group, 256 thr = 2 planes x 64 rows x 2 halves ----
    const int tl  = t & 255;
    const int spl = tl >> 7;                  // plane
    const int row = (tl & 127) >> 1;          // 0..63
    const int sq  = tl & 1;                   // half (32 u16)
    const int sr7 = row & 7;
    const u16* Kg = (spl ? Klo : Khi) + ((size_t)hb * L_ + row) * HD_ + sq * 32;
    u16* wdst0 = &kls[kg][0][spl][row * 64];
    u16* wdst1 = &kls[kg][1][spl][row * 64];

    const int sl0 = (lhi ^ (kc & 7)) * 8;     // read slots (dh=0, dh=1)
    const int sl1 = ((4 + lhi) ^ (kc & 7)) * 8;

    float lv0 = 0.f, wv0 = 0.f, lv1 = 0.f, wv1 = 0.f;

    uint4 ra[4], rb[4];
    // T(j) = 2*j + kg, j = 0..15
#define LOADT(RX, J) { const u16* src_ = Kg + (size_t)(2*(J) + kg) * 4096; \
    RX[0] = *(const uint4*)src_;        RX[1] = *(const uint4*)(src_ + 8); \
    RX[2] = *(const uint4*)(src_ + 16); RX[3] = *(const uint4*)(src_ + 24); }
#define WRT(DST, RX) { \
    *(uint4*)&DST[((sq*4 + 0) ^ sr7) * 8] = RX[0]; \
    *(uint4*)&DST[((sq*4 + 1) ^ sr7) * 8] = RX[1]; \
    *(uint4*)&DST[((sq*4 + 2) ^ sr7) * 8] = RX[2]; \
    *(uint4*)&DST[((sq*4 + 3) ^ sr7) * 8] = RX[3]; }
#define CTILE(J, BS) { \
    const int TI_ = 2*(J) + kg; \
    const u16* bh_ = &kls[kg][BS][0][0]; const u16* bl_ = &kls[kg][BS][1][0]; \
    f32x4 acc[4][2]; \
    _Pragma("unroll") for (int kf = 0; kf < 4; ++kf) { \
        acc[kf][0] = (f32x4){0.f,0.f,0.f,0.f}; acc[kf][1] = (f32x4){0.f,0.f,0.f,0.f}; } \
    __builtin_amdgcn_s_setprio(1); \
    _Pragma("unroll") for (int kf = 0; kf < 4; ++kf) { \
        const int rb_ = (kf*16 + kc) * 64; \
        const bf16x8 ah0 = *(const bf16x8*)&bh_[rb_ + sl0]; \
        const bf16x8 ah1 = *(const bf16x8*)&bh_[rb_ + sl1]; \
        const bf16x8 al0 = *(const bf16x8*)&bl_[rb_ + sl0]; \
        const bf16x8 al1 = *(const bf16x8*)&bl_[rb_ + sl1]; \
        _Pragma("unroll") for (int qf = 0; qf < 2; ++qf) { \
            acc[kf][qf] = __builtin_amdgcn_mfma_f32_16x16x32_bf16(ah0, qh[qf][0],  acc[kf][qf], 0, 0, 0); \
            acc[kf][qf] = __builtin_amdgcn_mfma_f32_16x16x32_bf16(ah1, qh[qf][1],  acc[kf][qf], 0, 0, 0); \
            acc[kf][qf] = __builtin_amdgcn_mfma_f32_16x16x32_bf16(ah0, ql2[qf][0], acc[kf][qf], 0, 0, 0); \
            acc[kf][qf] = __builtin_amdgcn_mfma_f32_16x16x32_bf16(ah1, ql2[qf][1], acc[kf][qf], 0, 0, 0); \
            acc[kf][qf] = __builtin_amdgcn_mfma_f32_16x16x32_bf16(al0, qh[qf][0],  acc[kf][qf], 0, 0, 0); \
            acc[kf][qf] = __builtin_amdgcn_mfma_f32_16x16x32_bf16(al1, qh[qf][1],  acc[kf][qf], 0, 0, 0); \
        } \
    } \
    __builtin_amdgcn_s_setprio(0); \
    _Pragma("unroll") for (int qf = 0; qf < 2; ++qf) { \
        const float dbf = (float)(TI_*64 + (qf ? d0q1 : d0q0)); \
        const float t2b = fmaf(dbf, A2, B2); \
        float S0 = 0.f, S1 = 0.f; \
        _Pragma("unroll") for (int kf = 0; kf < 4; ++kf) \
            _Pragma("unroll") for (int r = 0; r < 4; ++r) { \
                const int cc = kf*16 + r; \
                const float t2c = fmaf((float)cc, A2, t2b); \
                const float pr  = fast_exp2(fmaf(-t2c, t2c, LC)); \
                const float e   = fast_exp2(acc[kf][qf][r] * pr); \
                S0 += e; if (cc) S1 = fmaf(e, (float)cc, S1); \
            } \
        if (qf == 0) { lv0 += S0; wv0 = fmaf(dbf, S0, wv0 + S1); } \
        else         { lv1 += S0; wv1 = fmaf(dbf, S0, wv1 + S1); } \
    } \
}

    // prologue: T(0) -> buf0; T(1) -> regs ra
    LOADT(ra, 0); WRT(wdst0, ra);
    LOADT(ra, 1);
    __syncthreads();

    for (int j = 0; j < 16; j += 2) {
        // even: write T(j+1)->buf1, compute T(j) from buf0
        if (j + 2 < 16) LOADT(rb, j + 2);
        WRT(wdst1, ra);
        CTILE(j, 0);
        __syncthreads();
        // odd: write T(j+2)->buf0, compute T(j+1) from buf1
        if (j + 3 < 16) LOADT(ra, j + 3);
        if (j + 2 < 16) WRT(wdst0, rb);
        CTILE(j + 1, 1);
        __syncthreads();
    }
#undef LOADT
#undef WRT
#undef CTILE

    // intra-wave reduce across lhi groups (k-direction)
    lv0 += __shfl_xor(lv0, 16); wv0 += __shfl_xor(wv0, 16);
    lv0 += __shfl_xor(lv0, 32); wv0 += __shfl_xor(wv0, 32);
    lv1 += __shfl_xor(lv1, 16); wv1 += __shfl_xor(wv1, 16);
    lv1 += __shfl_xor(lv1, 32); wv1 += __shfl_xor(wv1, 32);

    // cross-group merge via LDS
    if (lhi == 0)      red2[kg][w4*32 + kc]      = make_float2(lv0, wv0);
    else if (lhi == 1) red2[kg][w4*32 + 16 + kc] = make_float2(lv1, wv1);
    __syncthreads();

    if (t < 128) {
        const float2 a = red2[0][t], c = red2[1][t];
        const float lv = a.x + c.x, wv = a.y + c.y;
        const int q = q0 + t;
        out[((size_t)(b * L_ + q)) * H_ + h] = (wv * iml) / lv;
    }
}

// ---------------------------------------------------------------------------
extern "C" void kernel_launch(void* const* d_in, const int* in_sizes, int n_in,
                              void* d_out, int out_size, void* d_ws, size_t ws_size,
                              hipStream_t stream)
{
    const float* x   = (const float*)d_in[0];
    const float* Wq  = (const float*)d_in[1];
    const float* bq  = (const float*)d_in[2];
    const float* Wk  = (const float*)d_in[3];
    const float* bk  = (const float*)d_in[4];
    const float* pm  = (const float*)d_in[5];
    const float* lps = (const float*)d_in[6];
    const int*   mlp = (const int*)d_in[7];
    float* out = (float*)d_out;

    u16* Qhi = (u16*)d_ws;                   // 4 planes x 8 MiB = 32 MiB (proven)
    u16* Qlo = Qhi + 4194304;
    u16* Khi = Qlo + 4194304;
    u16* Klo = Khi + 4194304;

    projB_kernel<<<dim3(64, 8, 2), 256, 0, stream>>>(x, Wq, bq, Wk, bk,
                                                     Qhi, Qlo, Khi, Klo);
    attn_kernel<<<dim3(512), 512, 0, stream>>>(Qhi, Qlo, Khi, Klo, pm, lps, mlp, out);
}